// Round 1
// baseline (8427.522 us; speedup 1.0000x reference)
//
#include <hip/hip_runtime.h>
#include <hip/hip_bf16.h>
#include <math.h>

// Problem constants (from reference)
constexpr int NN    = 2048;   // batch
constexpr int KO    = 8;      // objects / scan steps
constexpr int IH    = 128, IW = 128;
constexpr int GS    = 50;     // glimpse grid
constexpr int GG2   = GS*GS;  // 2500
constexpr int ENCD  = 100;
constexpr int HIDD  = 256;
constexpr int DREL  = 462;    // 100 + 3+3+50+50 + 256
constexpr int DTEM  = 2862;   // 2500 + 3+3+50+50 + 256

__device__ __forceinline__ float sigm(float x) { return 1.f/(1.f+expf(-x)); }

// ---------------- zero fill ----------------
__global__ void zero_kernel(float* __restrict__ p, int n) {
    int i = blockIdx.x*blockDim.x + threadIdx.x;
    if (i < n) p[i] = 0.f;
}

// ---------------- zwb = relu(hl @ W_loca^T + b) + zwl ----------------
__global__ void zwb_kernel(const float* __restrict__ hidden_last,
                           const float* __restrict__ z_where_last,
                           const float* __restrict__ Wl, const float* __restrict__ bl,
                           float* __restrict__ zwb, int k) {
    int gid = blockIdx.x*blockDim.x + threadIdx.x;
    if (gid >= NN*3) return;
    int n = gid/3, j = gid - n*3;
    const float* hl = hidden_last + ((size_t)n*KO + k)*HIDD;
    const float* w  = Wl + j*HIDD;
    float acc = bl[j];
    for (int i=0;i<HIDD;i++) acc = fmaf(hl[i], w[i], acc);
    acc = fmaxf(acc, 0.f);
    zwb[gid] = acc + z_where_last[((size_t)n*KO + k)*3 + j];
}

// ---------------- STN bilinear glimpse ----------------
__global__ __launch_bounds__(256) void glimpse_kernel(const float* __restrict__ img,
                                                      const float* __restrict__ zw,
                                                      float* __restrict__ dst, int dstStride) {
    int n = blockIdx.x;
    const float* im = img + (size_t)n*IH*IW;
    float s  = zw[n*3+0];
    float tx = zw[n*3+1];
    float ty = zw[n*3+2];
    for (int p = threadIdx.x; p < GG2; p += 256) {
        int i = p / GS, j = p - i*GS;
        float gx = -1.f + 2.f*j/(GS-1);
        float gy = -1.f + 2.f*i/(GS-1);
        float px = (s*gx + tx + 1.f)*0.5f*(IW-1);
        float py = (s*gy + ty + 1.f)*0.5f*(IH-1);
        float x0 = floorf(px), y0 = floorf(py);
        float wx1 = px - x0, wy1 = py - y0;
        int x0i = (int)x0, y0i = (int)y0;
        auto gat = [&](int yi, int xi)->float {
            bool valid = (yi>=0) & (yi<IH) & (xi>=0) & (xi<IW);
            int yc = min(max(yi,0),IH-1), xc = min(max(xi,0),IW-1);
            float v = im[yc*IW + xc];
            return valid ? v : 0.f;
        };
        float v = (1.f-wy1)*(1.f-wx1)*gat(y0i,   x0i)
                + (1.f-wy1)*     wx1 *gat(y0i,   x0i+1)
                +      wy1 *(1.f-wx1)*gat(y0i+1, x0i)
                +      wy1 *     wx1 *gat(y0i+1, x0i+1);
        dst[(size_t)n*dstStride + p] = v;
    }
}

// ---------------- generic fp32 GEMM: C[N][M] (+)= A[N][Kd] @ W[M][Kd]^T ----------------
// flags: 1 = accumulate into C, 2 = relu
__global__ __launch_bounds__(256) void sgemm(const float* __restrict__ A, int lda, int Kd,
                                             const float* __restrict__ Wt, int ldw, int M,
                                             const float* __restrict__ b1, const float* __restrict__ b2,
                                             float* __restrict__ C, int ldc, int flags) {
    __shared__ float As[16][68];
    __shared__ float Bs[16][68];
    int tid = threadIdx.x;
    int m0 = blockIdx.x*64;
    int n0 = blockIdx.y*64;
    int r  = tid >> 2;
    int kq = (tid & 3) << 2;
    int tx = tid & 15, ty = tid >> 4;
    float acc[4][4] = {};
    for (int k0 = 0; k0 < Kd; k0 += 16) {
        const float* Ap = A + (size_t)(n0+r)*lda + k0 + kq;
        #pragma unroll
        for (int u=0;u<4;u++)
            As[kq+u][r] = (k0+kq+u < Kd) ? Ap[u] : 0.f;
        bool mv = (m0 + r) < M;
        const float* Wp = Wt + (size_t)(m0+r)*ldw + k0 + kq;
        #pragma unroll
        for (int u=0;u<4;u++)
            Bs[kq+u][r] = (mv && (k0+kq+u < Kd)) ? Wp[u] : 0.f;
        __syncthreads();
        #pragma unroll
        for (int kk=0;kk<16;kk++) {
            float4 av = *(const float4*)&As[kk][ty<<2];
            float4 bv = *(const float4*)&Bs[kk][tx<<2];
            float a_[4] = {av.x, av.y, av.z, av.w};
            float b_[4] = {bv.x, bv.y, bv.z, bv.w};
            #pragma unroll
            for (int i=0;i<4;i++)
                #pragma unroll
                for (int j=0;j<4;j++)
                    acc[i][j] = fmaf(a_[i], b_[j], acc[i][j]);
        }
        __syncthreads();
    }
    #pragma unroll
    for (int i=0;i<4;i++) {
        int n = n0 + (ty<<2) + i;
        #pragma unroll
        for (int j=0;j<4;j++) {
            int m = m0 + (tx<<2) + j;
            if (m < M) {
                float v = acc[i][j];
                if (b1) v += b1[m];
                if (b2) v += b2[m];
                float* cp = C + (size_t)n*ldc + m;
                if (flags & 1) v += *cp;
                if (flags & 2) v = fmaxf(v, 0.f);
                *cp = v;
            }
        }
    }
}

// ---------------- concat fills ----------------
// rin cols 100..462 : [zwl(3), pzw(3), zwhatl(50), pzwhat(50), hl(256)]
__global__ void fill_rin(float* __restrict__ rin,
                         const float* __restrict__ z_where_last,
                         const float* __restrict__ pzw,
                         const float* __restrict__ z_what_last,
                         const float* __restrict__ pzwhat,
                         const float* __restrict__ hidden_last, int k) {
    int gid = blockIdx.x*blockDim.x + threadIdx.x;
    if (gid >= NN*362) return;
    int n = gid/362, c = gid - n*362;
    float v;
    if      (c <   3) v = z_where_last[((size_t)n*KO + k)*3 + c];
    else if (c <   6) v = pzw[n*3 + c-3];
    else if (c <  56) v = z_what_last[((size_t)n*KO + k)*50 + c-6];
    else if (c < 106) v = pzwhat[n*50 + c-56];
    else              v = hidden_last[((size_t)n*KO + k)*HIDD + c-106];
    rin[(size_t)n*DREL + 100 + c] = v;
}

// tin cols 2500..2862 : [zw(3), pzw(3), zwhatl(50), pzwhat(50), hl(256)]
__global__ void fill_tin(float* __restrict__ tin,
                         const float* __restrict__ zw_cur,
                         const float* __restrict__ pzw,
                         const float* __restrict__ z_what_last,
                         const float* __restrict__ pzwhat,
                         const float* __restrict__ hidden_last, int k) {
    int gid = blockIdx.x*blockDim.x + threadIdx.x;
    if (gid >= NN*362) return;
    int n = gid/362, c = gid - n*362;
    float v;
    if      (c <   3) v = zw_cur[n*3 + c];
    else if (c <   6) v = pzw[n*3 + c-3];
    else if (c <  56) v = z_what_last[((size_t)n*KO + k)*50 + c-6];
    else if (c < 106) v = pzwhat[n*50 + c-56];
    else              v = hidden_last[((size_t)n*KO + k)*HIDD + c-106];
    tin[(size_t)n*DTEM + 2500 + c] = v;
}

// ---------------- LSTM gate elementwise ----------------
__global__ void lstm_rel(const float* __restrict__ gates,
                         float* __restrict__ h, float* __restrict__ c) {
    int gid = blockIdx.x*blockDim.x + threadIdx.x;
    if (gid >= NN*HIDD) return;
    int n = gid >> 8, j = gid & 255;
    const float* g = gates + (size_t)n*1024;
    float ig = sigm(g[j]);
    float fg = sigm(g[256+j]);
    float gg = tanhf(g[512+j]);
    float og = sigm(g[768+j]);
    float c2 = fg*c[gid] + ig*gg;
    c[gid] = c2;
    h[gid] = og*tanhf(c2);
}

__global__ void lstm_tem(const float* __restrict__ gates,
                         const float* __restrict__ c_in,
                         float* __restrict__ h_t,
                         float* __restrict__ out_htemp, int k) {
    int gid = blockIdx.x*blockDim.x + threadIdx.x;
    if (gid >= NN*HIDD) return;
    int n = gid >> 8, j = gid & 255;
    const float* g = gates + (size_t)n*1024;
    float ig = sigm(g[j]);
    float fg = sigm(g[256+j]);
    float gg = tanhf(g[512+j]);
    float og = sigm(g[768+j]);
    float c2 = fg*c_in[gid] + ig*gg;
    float hv = og*tanhf(c2);
    h_t[gid] = hv;
    out_htemp[((size_t)n*KO + k)*HIDD + j] = hv;
}

// ---------------- zw = [zwl, h_r2] @ Wm_wh^T + b ----------------
__global__ void zw_kernel(const float* __restrict__ z_where_last,
                          const float* __restrict__ h_r,
                          const float* __restrict__ Wm, const float* __restrict__ bm,
                          float* __restrict__ zw_cur, float* __restrict__ out_zwhere, int k) {
    int gid = blockIdx.x*blockDim.x + threadIdx.x;
    if (gid >= NN*3) return;
    int n = gid/3, j = gid - n*3;
    const float* w = Wm + j*(3+HIDD);
    float acc = bm[j];
    const float* zwl = z_where_last + ((size_t)n*KO + k)*3;
    for (int i=0;i<3;i++)    acc = fmaf(zwl[i], w[i], acc);
    const float* h = h_r + (size_t)n*HIDD;
    for (int i=0;i<HIDD;i++) acc = fmaf(h[i], w[3+i], acc);
    zw_cur[gid] = acc;
    out_zwhere[((size_t)n*KO + k)*3 + j] = acc;
}

// ---------------- zwhat = [zwhatl, h_r2, h_t] @ Wm_wt^T + b ----------------
__global__ void zwhat_kernel(const float* __restrict__ z_what_last,
                             const float* __restrict__ h_r, const float* __restrict__ h_t,
                             const float* __restrict__ Wm, const float* __restrict__ bm,
                             float* __restrict__ zwhat_cur, float* __restrict__ out_zwhat, int k) {
    int gid = blockIdx.x*blockDim.x + threadIdx.x;
    if (gid >= NN*50) return;
    int n = gid/50, m = gid - n*50;
    const float* w = Wm + m*562;
    float acc = bm[m];
    const float* zl = z_what_last + ((size_t)n*KO + k)*50;
    for (int i=0;i<50;i++)   acc = fmaf(zl[i], w[i], acc);
    const float* hr = h_r + (size_t)n*HIDD;
    for (int i=0;i<HIDD;i++) acc = fmaf(hr[i], w[50+i], acc);
    const float* ht = h_t + (size_t)n*HIDD;
    for (int i=0;i<HIDD;i++) acc = fmaf(ht[i], w[306+i], acc);
    zwhat_cur[gid] = acc;
    out_zwhat[((size_t)n*KO + k)*50 + m] = acc;
}

// ---------------- z_pres: p = sig(zp_cal@Wm+bm)*sig(zp_cal@Ws+bs) * zpl ----------------
__global__ __launch_bounds__(256) void pres_kernel(const float* __restrict__ zwhat,
                                                   const float* __restrict__ zw,
                                                   const float* __restrict__ h_r,
                                                   const float* __restrict__ h_t,
                                                   const float* __restrict__ Wm, const float* __restrict__ bm,
                                                   const float* __restrict__ Ws, const float* __restrict__ bs,
                                                   const float* __restrict__ z_pres_last,
                                                   float* __restrict__ out_zpres, int k) {
    int wave = threadIdx.x >> 6;
    int lane = threadIdx.x & 63;
    int n = blockIdx.x*4 + wave;
    float s1 = 0.f, s2 = 0.f;
    for (int idx = lane; idx < 565; idx += 64) {
        float v;
        if      (idx <  50) v = zwhat[(size_t)n*50 + idx];
        else if (idx <  53) v = zw[(size_t)n*3 + idx-50];
        else if (idx < 309) v = h_r[(size_t)n*HIDD + idx-53];
        else                v = h_t[(size_t)n*HIDD + idx-309];
        s1 = fmaf(v, Wm[idx], s1);
        s2 = fmaf(v, Ws[idx], s2);
    }
    #pragma unroll
    for (int off=32; off; off>>=1) { s1 += __shfl_down(s1,off); s2 += __shfl_down(s2,off); }
    if (lane == 0) {
        float p = sigm(s1 + bm[0]) * sigm(s2 + bs[0]);
        out_zpres[(size_t)n*KO + k] = p * z_pres_last[(size_t)n*KO + k];
    }
}

extern "C" void kernel_launch(void* const* d_in, const int* in_sizes, int n_in,
                              void* d_out, int out_size, void* d_ws, size_t ws_size,
                              hipStream_t stream) {
    (void)in_sizes; (void)n_in; (void)out_size; (void)ws_size;
    const float* img          = (const float*)d_in[0];
    const float* z_what_last  = (const float*)d_in[1];
    const float* z_where_last = (const float*)d_in[2];
    const float* z_pres_last  = (const float*)d_in[3];
    const float* hidden_last  = (const float*)d_in[4];
    const float* W_loca = (const float*)d_in[5];
    const float* b_loca = (const float*)d_in[6];
    const float* Wg     = (const float*)d_in[7];
    const float* bg     = (const float*)d_in[8];
    const float* Wih_rel = (const float*)d_in[9];
    const float* Whh_rel = (const float*)d_in[10];
    const float* bih_rel = (const float*)d_in[11];
    const float* bhh_rel = (const float*)d_in[12];
    const float* Wih_tem = (const float*)d_in[13];
    const float* Whh_tem = (const float*)d_in[14];
    const float* bih_tem = (const float*)d_in[15];
    const float* bhh_tem = (const float*)d_in[16];
    const float* Wm_wh = (const float*)d_in[17];
    const float* bm_wh = (const float*)d_in[18];
    // 19,20 (Ws_wh, bs_wh) unused by reference
    const float* Wm_wt = (const float*)d_in[21];
    const float* bm_wt = (const float*)d_in[22];
    // 23,24 (Ws_wt, bs_wt) unused by reference
    const float* Wm_pr = (const float*)d_in[25];
    const float* bm_pr = (const float*)d_in[26];
    const float* Ws_pr = (const float*)d_in[27];
    const float* bs_pr = (const float*)d_in[28];

    float* ws = (float*)d_ws;
    size_t off = 0;
    float* tin    = ws + off; off += (size_t)NN*DTEM;   // glimpse writes cols 0..2500 directly
    float* rin    = ws + off; off += (size_t)NN*DREL;
    float* gates  = ws + off; off += (size_t)NN*1024;
    float* h_r    = ws + off; off += (size_t)NN*HIDD;   // zeroed (carry)
    float* c_r    = ws + off; off += (size_t)NN*HIDD;   // zeroed (carry)
    float* zw1    = ws + off; off += (size_t)NN*3;      // zeroed (pzw @ k=0)
    float* zwhat1 = ws + off; off += (size_t)NN*50;     // zeroed (pzwhat @ k=0)
    float* h_t    = ws + off; off += (size_t)NN*HIDD;
    float* zwb    = ws + off; off += (size_t)NN*3;
    float* zw0    = ws + off; off += (size_t)NN*3;
    float* zwhat0 = ws + off; off += (size_t)NN*50;

    float* out        = (float*)d_out;
    float* out_zwhat  = out;
    float* out_zwhere = out + (size_t)NN*KO*50;
    float* out_zpres  = out_zwhere + (size_t)NN*KO*3;
    float* out_htemp  = out_zpres + (size_t)NN*KO;

    // zero carry: h_r, c_r, zw1, zwhat1 are contiguous
    {
        int nz = NN*(HIDD + HIDD + 3 + 50);
        zero_kernel<<<(nz+255)/256, 256, 0, stream>>>(h_r, nz);
    }

    for (int k = 0; k < KO; ++k) {
        float* zw_cur     = (k & 1) ? zw1 : zw0;
        float* zw_prev    = (k & 1) ? zw0 : zw1;
        float* zwhat_cur  = (k & 1) ? zwhat1 : zwhat0;
        float* zwhat_prev = (k & 1) ? zwhat0 : zwhat1;

        // 1. zwb = relu(hl@W_loca^T + b) + zwl
        zwb_kernel<<<(NN*3+255)/256, 256, 0, stream>>>(hidden_last, z_where_last, W_loca, b_loca, zwb, k);
        // 2. glimpse1 -> tin[:, 0:2500]
        glimpse_kernel<<<NN, 256, 0, stream>>>(img, zwb, tin, DTEM);
        // 3. enc = relu(g1 @ Wg^T + bg) -> rin[:, 0:100]
        sgemm<<<dim3(2, NN/64), 256, 0, stream>>>(tin, DTEM, GG2, Wg, GG2, ENCD, bg, nullptr, rin, DREL, 2);
        // 4. fill rin cols 100..462
        fill_rin<<<(NN*362+255)/256, 256, 0, stream>>>(rin, z_where_last, zw_prev, z_what_last, zwhat_prev, hidden_last, k);
        // 5. gates = rin @ Wih_rel^T + bih + bhh
        sgemm<<<dim3(16, NN/64), 256, 0, stream>>>(rin, DREL, DREL, Wih_rel, DREL, 1024, bih_rel, bhh_rel, gates, 1024, 0);
        // 6. gates += h_r @ Whh_rel^T
        sgemm<<<dim3(16, NN/64), 256, 0, stream>>>(h_r, HIDD, HIDD, Whh_rel, HIDD, 1024, nullptr, nullptr, gates, 1024, 1);
        // 7. rel LSTM elementwise: h_r, c_r updated in place
        lstm_rel<<<(NN*HIDD+255)/256, 256, 0, stream>>>(gates, h_r, c_r);
        // 8. zw = [zwl, h_r2] @ Wm_wh^T + bm_wh  (+ write z_where output)
        zw_kernel<<<(NN*3+255)/256, 256, 0, stream>>>(z_where_last, h_r, Wm_wh, bm_wh, zw_cur, out_zwhere, k);
        // 9. glimpse2 -> tin[:, 0:2500]
        glimpse_kernel<<<NN, 256, 0, stream>>>(img, zw_cur, tin, DTEM);
        // 10. fill tin cols 2500..2862
        fill_tin<<<(NN*362+255)/256, 256, 0, stream>>>(tin, zw_cur, zw_prev, z_what_last, zwhat_prev, hidden_last, k);
        // 11. gates = tin @ Wih_tem^T + bih + bhh
        sgemm<<<dim3(16, NN/64), 256, 0, stream>>>(tin, DTEM, DTEM, Wih_tem, DTEM, 1024, bih_tem, bhh_tem, gates, 1024, 0);
        // 12. gates += h_r2 @ Whh_tem^T
        sgemm<<<dim3(16, NN/64), 256, 0, stream>>>(h_r, HIDD, HIDD, Whh_tem, HIDD, 1024, nullptr, nullptr, gates, 1024, 1);
        // 13. tem LSTM elementwise -> h_t (c_t discarded; c_r preserved) + h_temp output
        lstm_tem<<<(NN*HIDD+255)/256, 256, 0, stream>>>(gates, c_r, h_t, out_htemp, k);
        // 14. zwhat = [zwhatl, h_r2, h_t] @ Wm_wt^T + bm_wt (+ z_what output)
        zwhat_kernel<<<(NN*50+255)/256, 256, 0, stream>>>(z_what_last, h_r, h_t, Wm_wt, bm_wt, zwhat_cur, out_zwhat, k);
        // 15. z_pres
        pres_kernel<<<NN/4, 256, 0, stream>>>(zwhat_cur, zw_cur, h_r, h_t, Wm_pr, bm_pr, Ws_pr, bs_pr, z_pres_last, out_zpres, k);
    }
}

// Round 2
// 1647.067 us; speedup vs baseline: 5.1167x; 5.1167x over previous
//
#include <hip/hip_runtime.h>
#include <hip/hip_bf16.h>
#include <math.h>

typedef __attribute__((ext_vector_type(8))) short bf16x8;
typedef __attribute__((ext_vector_type(4))) float f32x4;
using bf16 = __hip_bfloat16;

constexpr int NN   = 2048;
constexpr int KO   = 8;
constexpr int IH   = 128, IW = 128;
constexpr int GS   = 50;
constexpr int GG2  = GS*GS;      // 2500
constexpr int HIDD = 256;
// rin layout: [enc 0..100 | zwl 100..103 | pzw 103..106 | zwhatl 106..156 | pzwhat 156..206 | hl 206..462 | h_r 462..718 | pad..736]
constexpr int RIN_LD = 736;
// tin layout: [g2 0..2500 | zw 2500..2503 | pzw 2503..2506 | zwhatl 2506..2556 | pzwhat 2556..2606 | hl 2606..2862 | h_r2 2862..3118 | pad..3136]
constexpr int TIN_LD = 3136;
constexpr int G1_LD  = 2528;     // 2500 + zero-padded weight cols

__device__ __forceinline__ float sigm(float x) { return 1.f/(1.f+expf(-x)); }

// ================= MFMA GEMM: C[N][M] = A[N][Kd] @ W[M][Kd]^T (+bias, relu, bf16/f32 out) ==========
// Tile: BN=128 rows x BM=64 cols, BK=32. 256 threads = 4 waves, each wave 64x32.
template<int OUT_BF16, int RELU>
__global__ __launch_bounds__(256) void mfma_gemm(
    const bf16* __restrict__ A, int lda, int Kd,
    const bf16* __restrict__ Wt, int ldw, int M,
    const float* __restrict__ b1, const float* __restrict__ b2,
    void* __restrict__ Cout, int ldc)
{
    constexpr int PAD = 40;                       // bf16 elems per LDS row (32 + 8 pad)
    __shared__ bf16 As[128*PAD];
    __shared__ bf16 Bs[64*PAD];
    const int tid  = threadIdx.x;
    const int n0   = blockIdx.y*128;
    const int m0   = blockIdx.x*64;
    const int wave = tid>>6, lane = tid&63;
    const int q    = lane>>4, r = lane&15;
    const int wy   = wave>>1, wx = wave&1;        // wave tile: rows wy*64, cols wx*32

    const int arow = tid>>2, apart = tid&3;       // staging: 16B segs
    const bf16* A0 = A  + (size_t)(n0+arow)*lda    + apart*8;
    const bf16* A1 = A  + (size_t)(n0+arow+64)*lda + apart*8;
    const int   wm = m0 + arow;
    const bf16* Wp = Wt + (size_t)(wm < M ? wm : M-1)*ldw + apart*8;
    bf16* lA0 = &As[(arow   )*PAD + apart*8];
    bf16* lA1 = &As[(arow+64)*PAD + apart*8];
    bf16* lW  = &Bs[(arow   )*PAD + apart*8];
    const bf16* rA = &As[(wy*64 + r)*PAD + q*8];
    const bf16* rB = &Bs[(wx*32 + r)*PAD + q*8];

    f32x4 acc[4][2] = {};
    const bf16x8 z8 = {};

    for (int k0 = 0; k0 < Kd; k0 += 32) {
        bf16x8 a1 = *(const bf16x8*)(A0 + k0);
        bf16x8 a2 = *(const bf16x8*)(A1 + k0);
        bf16x8 wv = *(const bf16x8*)(Wp + k0);
        if (wm >= M) wv = z8;
        __syncthreads();
        *(bf16x8*)lA0 = a1;
        *(bf16x8*)lA1 = a2;
        *(bf16x8*)lW  = wv;
        __syncthreads();
        bf16x8 av[4], bv[2];
        #pragma unroll
        for (int i=0;i<4;i++) av[i] = *(const bf16x8*)(rA + i*16*PAD);
        #pragma unroll
        for (int j=0;j<2;j++) bv[j] = *(const bf16x8*)(rB + j*16*PAD);
        #pragma unroll
        for (int i=0;i<4;i++)
            #pragma unroll
            for (int j=0;j<2;j++)
                acc[i][j] = __builtin_amdgcn_mfma_f32_16x16x32_bf16(av[i], bv[j], acc[i][j], 0, 0, 0);
    }

    const int crow = n0 + wy*64 + q*4;
    const int ccol = m0 + wx*32 + r;
    #pragma unroll
    for (int j=0;j<2;j++) {
        int col = ccol + j*16;
        if (col < M) {
            float bias = 0.f;
            if (b1) bias += b1[col];
            if (b2) bias += b2[col];
            #pragma unroll
            for (int i=0;i<4;i++) {
                #pragma unroll
                for (int reg=0;reg<4;reg++) {
                    float v = acc[i][j][reg] + bias;
                    if (RELU) v = fmaxf(v, 0.f);
                    size_t idx = (size_t)(crow + i*16 + reg)*ldc + col;
                    if (OUT_BF16) ((bf16*)Cout)[idx] = __float2bfloat16(v);
                    else          ((float*)Cout)[idx] = v;
                }
            }
        }
    }
}

// ================= small kernels =================
__global__ void zero_f32(float* __restrict__ p, int n) {
    int i = blockIdx.x*blockDim.x + threadIdx.x;
    if (i < n) p[i] = 0.f;
}

// repack W as bf16: cols [0,K1) from s1, [K1,K1+K2) from s2, rest 0
__global__ void repack_w(const float* __restrict__ s1, int K1,
                         const float* __restrict__ s2, int K2,
                         bf16* __restrict__ dst, int ldd, int M) {
    int gid = blockIdx.x*blockDim.x + threadIdx.x;
    if (gid >= M*ldd) return;
    int m = gid / ldd, c = gid - m*ldd;
    float v = 0.f;
    if (c < K1)           v = s1[(size_t)m*K1 + c];
    else if (c < K1+K2)   v = s2[(size_t)m*K2 + (c-K1)];
    dst[gid] = __float2bfloat16(v);
}

// zwb for all 8 steps (input-only): zwb = relu(hl@W_loca^T + b) + zwl
__global__ void zwb_all_kernel(const float* __restrict__ hidden_last,
                               const float* __restrict__ z_where_last,
                               const float* __restrict__ Wl, const float* __restrict__ bl,
                               float* __restrict__ zwb_all) {
    int gid = blockIdx.x*blockDim.x + threadIdx.x;
    if (gid >= KO*NN*3) return;
    int j = gid % 3; int rn = gid/3; int n = rn & (NN-1); int s = rn >> 11;
    const float* hl = hidden_last + ((size_t)n*KO + s)*HIDD;
    const float* w  = Wl + j*HIDD;
    float acc = bl[j];
    for (int i=0;i<HIDD;i++) acc = fmaf(hl[i], w[i], acc);
    zwb_all[gid] = fmaxf(acc, 0.f) + z_where_last[((size_t)n*KO + s)*3 + j];
}

// STN bilinear glimpse -> bf16. blockIdx = (step*NN + n) for batched, img index = blockIdx & (NN-1)
__global__ __launch_bounds__(256) void glimpse_kernel(const float* __restrict__ img,
                                                      const float* __restrict__ z,
                                                      bf16* __restrict__ dst, int ldd) {
    int b = blockIdx.x;
    const float* im = img + (size_t)(b & (NN-1))*IH*IW;
    float s  = z[b*3+0];
    float tx = z[b*3+1];
    float ty = z[b*3+2];
    for (int p = threadIdx.x; p < GG2; p += 256) {
        int i = p / GS, j = p - i*GS;
        float gx = -1.f + 2.f*j/(GS-1);
        float gy = -1.f + 2.f*i/(GS-1);
        float px = (s*gx + tx + 1.f)*0.5f*(IW-1);
        float py = (s*gy + ty + 1.f)*0.5f*(IH-1);
        float x0 = floorf(px), y0 = floorf(py);
        float wx1 = px - x0, wy1 = py - y0;
        int x0i = (int)x0, y0i = (int)y0;
        auto gat = [&](int yi, int xi)->float {
            bool valid = (yi>=0) & (yi<IH) & (xi>=0) & (xi<IW);
            int yc = min(max(yi,0),IH-1), xc = min(max(xi,0),IW-1);
            float v = im[yc*IW + xc];
            return valid ? v : 0.f;
        };
        float v = (1.f-wy1)*(1.f-wx1)*gat(y0i,   x0i)
                + (1.f-wy1)*     wx1 *gat(y0i,   x0i+1)
                +      wy1 *(1.f-wx1)*gat(y0i+1, x0i)
                +      wy1 *     wx1 *gat(y0i+1, x0i+1);
        dst[(size_t)b*ldd + p] = __float2bfloat16(v);
    }
}

// static rin cols for CH slots: zwl(100..103), zwhatl(106..156), hl(206..462)
__global__ void fill_rin_static(bf16* __restrict__ rin,
                                const float* __restrict__ z_where_last,
                                const float* __restrict__ z_what_last,
                                const float* __restrict__ hidden_last,
                                int base, int CH) {
    int gid = blockIdx.x*blockDim.x + threadIdx.x;
    if (gid >= CH*NN*309) return;
    int c = gid % 309; int rn = gid/309; int n = rn & (NN-1); int sl = rn >> 11;
    int k = base + sl;
    float v; int col;
    if (c < 3)       { col = 100 + c;      v = z_where_last[((size_t)n*KO + k)*3 + c]; }
    else if (c < 53) { col = 106 + (c-3);  v = z_what_last[((size_t)n*KO + k)*50 + (c-3)]; }
    else             { col = 206 + (c-53); v = hidden_last[((size_t)n*KO + k)*HIDD + (c-53)]; }
    rin[(size_t)rn*RIN_LD + col] = __float2bfloat16(v);
}

// zero carry cols of rin slot 0 (step 0): pzw(103..106), pzwhat(156..206), h_r(462..718)
__global__ void zero_rin_carry(bf16* __restrict__ rin0) {
    int gid = blockIdx.x*blockDim.x + threadIdx.x;
    if (gid >= NN*309) return;
    int c = gid % 309, n = gid/309;
    int col = (c < 3) ? 103+c : ((c < 53) ? 156+(c-3) : 462+(c-53));
    rin0[(size_t)n*RIN_LD + col] = __float2bfloat16(0.f);
}

// per-step tin fill: pzw(2503..2506), zwhatl(2506..2556), pzwhat(2556..2606), hl(2606..2862)
__global__ void fill_tin(bf16* __restrict__ tin,
                         const float* __restrict__ zw_prev,
                         const float* __restrict__ zwhat_prev,
                         const float* __restrict__ z_what_last,
                         const float* __restrict__ hidden_last, int k) {
    int gid = blockIdx.x*blockDim.x + threadIdx.x;
    if (gid >= NN*359) return;
    int c = gid % 359, n = gid/359;
    float v; int col;
    if (c < 3)        { col = 2503 + c;       v = zw_prev[n*3 + c]; }
    else if (c < 53)  { col = 2506 + (c-3);   v = z_what_last[((size_t)n*KO + k)*50 + (c-3)]; }
    else if (c < 103) { col = 2556 + (c-53);  v = zwhat_prev[n*50 + (c-53)]; }
    else              { col = 2606 + (c-103); v = hidden_last[((size_t)n*KO + k)*HIDD + (c-103)]; }
    tin[(size_t)n*TIN_LD + col] = __float2bfloat16(v);
}

__global__ void lstm_rel(const float* __restrict__ gates,
                         float* __restrict__ h, float* __restrict__ c,
                         bf16* __restrict__ rin_next, bf16* __restrict__ tin) {
    int gid = blockIdx.x*blockDim.x + threadIdx.x;
    if (gid >= NN*HIDD) return;
    int n = gid >> 8, j = gid & 255;
    const float* g = gates + (size_t)n*1024;
    float ig = sigm(g[j]);
    float fg = sigm(g[256+j]);
    float gg = tanhf(g[512+j]);
    float og = sigm(g[768+j]);
    float c2 = fg*c[gid] + ig*gg;
    float hv = og*tanhf(c2);
    c[gid] = c2;
    h[gid] = hv;
    bf16 hb = __float2bfloat16(hv);
    rin_next[(size_t)n*RIN_LD + 462 + j] = hb;
    tin[(size_t)n*TIN_LD + 2862 + j]     = hb;
}

__global__ void lstm_tem(const float* __restrict__ gates,
                         const float* __restrict__ c_in,
                         float* __restrict__ h_t,
                         float* __restrict__ out_htemp, int k) {
    int gid = blockIdx.x*blockDim.x + threadIdx.x;
    if (gid >= NN*HIDD) return;
    int n = gid >> 8, j = gid & 255;
    const float* g = gates + (size_t)n*1024;
    float ig = sigm(g[j]);
    float fg = sigm(g[256+j]);
    float gg = tanhf(g[512+j]);
    float og = sigm(g[768+j]);
    float c2 = fg*c_in[gid] + ig*gg;
    float hv = og*tanhf(c2);
    h_t[gid] = hv;
    out_htemp[((size_t)n*KO + k)*HIDD + j] = hv;
}

// zw = [zwl, h_r2] @ Wm_wh^T + b  (fp32 dot; writes fp32 buf + output + bf16 into tin & rin_next)
__global__ void zw_kernel(const float* __restrict__ z_where_last,
                          const float* __restrict__ h_r,
                          const float* __restrict__ Wm, const float* __restrict__ bm,
                          float* __restrict__ zw_cur, float* __restrict__ out_zwhere,
                          bf16* __restrict__ tin, bf16* __restrict__ rin_next, int k) {
    int gid = blockIdx.x*blockDim.x + threadIdx.x;
    if (gid >= NN*3) return;
    int n = gid/3, j = gid - n*3;
    const float* w = Wm + j*(3+HIDD);
    float acc = bm[j];
    const float* zwl = z_where_last + ((size_t)n*KO + k)*3;
    for (int i=0;i<3;i++)    acc = fmaf(zwl[i], w[i], acc);
    const float* h = h_r + (size_t)n*HIDD;
    for (int i=0;i<HIDD;i++) acc = fmaf(h[i], w[3+i], acc);
    zw_cur[gid] = acc;
    out_zwhere[((size_t)n*KO + k)*3 + j] = acc;
    bf16 ab = __float2bfloat16(acc);
    tin[(size_t)n*TIN_LD + 2500 + j]     = ab;
    rin_next[(size_t)n*RIN_LD + 103 + j] = ab;
}

// zwhat = [zwhatl, h_r2, h_t] @ Wm_wt^T + b (fp32; + bf16 into rin_next)
__global__ void zwhat_kernel(const float* __restrict__ z_what_last,
                             const float* __restrict__ h_r, const float* __restrict__ h_t,
                             const float* __restrict__ Wm, const float* __restrict__ bm,
                             float* __restrict__ zwhat_cur, float* __restrict__ out_zwhat,
                             bf16* __restrict__ rin_next, int k) {
    int gid = blockIdx.x*blockDim.x + threadIdx.x;
    if (gid >= NN*50) return;
    int n = gid/50, m = gid - n*50;
    const float* w = Wm + m*562;
    float acc = bm[m];
    const float* zl = z_what_last + ((size_t)n*KO + k)*50;
    for (int i=0;i<50;i++)   acc = fmaf(zl[i], w[i], acc);
    const float* hr = h_r + (size_t)n*HIDD;
    for (int i=0;i<HIDD;i++) acc = fmaf(hr[i], w[50+i], acc);
    const float* ht = h_t + (size_t)n*HIDD;
    for (int i=0;i<HIDD;i++) acc = fmaf(ht[i], w[306+i], acc);
    zwhat_cur[gid] = acc;
    out_zwhat[((size_t)n*KO + k)*50 + m] = acc;
    rin_next[(size_t)n*RIN_LD + 156 + m] = __float2bfloat16(acc);
}

__global__ __launch_bounds__(256) void pres_kernel(const float* __restrict__ zwhat,
                                                   const float* __restrict__ zw,
                                                   const float* __restrict__ h_r,
                                                   const float* __restrict__ h_t,
                                                   const float* __restrict__ Wm, const float* __restrict__ bm,
                                                   const float* __restrict__ Ws, const float* __restrict__ bs,
                                                   const float* __restrict__ z_pres_last,
                                                   float* __restrict__ out_zpres, int k) {
    int wave = threadIdx.x >> 6;
    int lane = threadIdx.x & 63;
    int n = blockIdx.x*4 + wave;
    float s1 = 0.f, s2 = 0.f;
    for (int idx = lane; idx < 565; idx += 64) {
        float v;
        if      (idx <  50) v = zwhat[(size_t)n*50 + idx];
        else if (idx <  53) v = zw[(size_t)n*3 + idx-50];
        else if (idx < 309) v = h_r[(size_t)n*HIDD + idx-53];
        else                v = h_t[(size_t)n*HIDD + idx-309];
        s1 = fmaf(v, Wm[idx], s1);
        s2 = fmaf(v, Ws[idx], s2);
    }
    #pragma unroll
    for (int off=32; off; off>>=1) { s1 += __shfl_down(s1,off); s2 += __shfl_down(s2,off); }
    if (lane == 0) {
        float p = sigm(s1 + bm[0]) * sigm(s2 + bs[0]);
        out_zpres[(size_t)n*KO + k] = p * z_pres_last[(size_t)n*KO + k];
    }
}

extern "C" void kernel_launch(void* const* d_in, const int* in_sizes, int n_in,
                              void* d_out, int out_size, void* d_ws, size_t ws_size,
                              hipStream_t stream) {
    (void)in_sizes; (void)n_in; (void)out_size;
    const float* img          = (const float*)d_in[0];
    const float* z_what_last  = (const float*)d_in[1];
    const float* z_where_last = (const float*)d_in[2];
    const float* z_pres_last  = (const float*)d_in[3];
    const float* hidden_last  = (const float*)d_in[4];
    const float* W_loca = (const float*)d_in[5];
    const float* b_loca = (const float*)d_in[6];
    const float* Wg     = (const float*)d_in[7];
    const float* bg     = (const float*)d_in[8];
    const float* Wih_rel = (const float*)d_in[9];
    const float* Whh_rel = (const float*)d_in[10];
    const float* bih_rel = (const float*)d_in[11];
    const float* bhh_rel = (const float*)d_in[12];
    const float* Wih_tem = (const float*)d_in[13];
    const float* Whh_tem = (const float*)d_in[14];
    const float* bih_tem = (const float*)d_in[15];
    const float* bhh_tem = (const float*)d_in[16];
    const float* Wm_wh = (const float*)d_in[17];
    const float* bm_wh = (const float*)d_in[18];
    const float* Wm_wt = (const float*)d_in[21];
    const float* bm_wt = (const float*)d_in[22];
    const float* Wm_pr = (const float*)d_in[25];
    const float* bm_pr = (const float*)d_in[26];
    const float* Ws_pr = (const float*)d_in[27];
    const float* bs_pr = (const float*)d_in[28];

    // ---- workspace layout (aligned 256B) ----
    char* base_p = (char*)d_ws;
    size_t off = 0;
    auto carve = [&](size_t bytes) -> char* {
        char* r = base_p + off;
        off += (bytes + 255) & ~(size_t)255;
        return r;
    };
    bf16*  tin      = (bf16*) carve((size_t)NN*TIN_LD*2);
    float* gates    = (float*)carve((size_t)NN*1024*4);
    bf16*  W_tem    = (bf16*) carve((size_t)1024*TIN_LD*2);
    bf16*  W_rel    = (bf16*) carve((size_t)1024*RIN_LD*2);
    bf16*  Wg_bf    = (bf16*) carve((size_t)100*G1_LD*2);
    float* zwb_all  = (float*)carve((size_t)KO*NN*3*4);
    float* h_r      = (float*)carve((size_t)NN*HIDD*4);
    float* h_t      = (float*)carve((size_t)NN*HIDD*4);
    // zero block: c_r, zw1, zwhat1 contiguous
    float* c_r      = (float*)carve((size_t)NN*HIDD*4);
    float* zw1      = (float*)carve((size_t)NN*3*4);
    float* zwhat1   = (float*)carve((size_t)NN*50*4);
    float* zw0      = (float*)carve((size_t)NN*3*4);
    float* zwhat0   = (float*)carve((size_t)NN*50*4);
    size_t fixed_bytes = off;

    // choose chunk size CH from remaining ws
    int CH = 1;
    for (int cand : {8, 4, 2}) {
        size_t need = fixed_bytes
                    + (((size_t)cand*NN*G1_LD*2 + 255) & ~(size_t)255)
                    + (((size_t)cand*NN*RIN_LD*2 + 255) & ~(size_t)255);
        if (need <= ws_size) { CH = cand; break; }
    }
    bf16* g1 = nullptr; int g1ld;
    bf16* rin;
    if (CH > 1) {
        g1   = (bf16*)carve((size_t)CH*NN*G1_LD*2);
        rin  = (bf16*)carve((size_t)CH*NN*RIN_LD*2);
        g1ld = G1_LD;
    } else {
        rin  = (bf16*)carve((size_t)NN*RIN_LD*2);
        g1   = tin;          // alias: glimpse1 -> tin cols 0..2500; Wg pad cols are zero
        g1ld = TIN_LD;
    }

    float* out        = (float*)d_out;
    float* out_zwhat  = out;
    float* out_zwhere = out + (size_t)NN*KO*50;
    float* out_zpres  = out_zwhere + (size_t)NN*KO*3;
    float* out_htemp  = out_zpres + (size_t)NN*KO;

    // ---- upfront (carry-independent) ----
    {
        int nz = NN*(HIDD + 3 + 50);   // c_r, zw1, zwhat1
        zero_f32<<<(nz+255)/256, 256, 0, stream>>>(c_r, nz);
    }
    zero_rin_carry<<<(NN*309+255)/256, 256, 0, stream>>>(rin);
    repack_w<<<((1024*RIN_LD)+255)/256, 256, 0, stream>>>(Wih_rel, 462, Whh_rel, 256, W_rel, RIN_LD, 1024);
    repack_w<<<((1024*TIN_LD)+255)/256, 256, 0, stream>>>(Wih_tem, 2862, Whh_tem, 256, W_tem, TIN_LD, 1024);
    repack_w<<<((100*G1_LD)+255)/256, 256, 0, stream>>>(Wg, 2500, nullptr, 0, Wg_bf, G1_LD, 100);
    zwb_all_kernel<<<(KO*NN*3+255)/256, 256, 0, stream>>>(hidden_last, z_where_last, W_loca, b_loca, zwb_all);

    for (int cbase = 0; cbase < KO; cbase += CH) {
        // chunk preamble: static rin cols, batched glimpse1 + enc
        fill_rin_static<<<(CH*NN*309+255)/256, 256, 0, stream>>>(rin, z_where_last, z_what_last, hidden_last, cbase, CH);
        glimpse_kernel<<<CH*NN, 256, 0, stream>>>(img, zwb_all + (size_t)cbase*NN*3, g1, g1ld);
        mfma_gemm<1,1><<<dim3(2, CH*16), 256, 0, stream>>>(g1, g1ld, G1_LD, Wg_bf, G1_LD, 100, bg, nullptr, rin, RIN_LD);

        for (int s = 0; s < CH; ++s) {
            int k = cbase + s;
            bf16* rin_k  = rin + (size_t)s*NN*RIN_LD;
            bf16* rin_nx = rin + (size_t)((s+1)%CH)*NN*RIN_LD;
            float* zw_cur     = (k & 1) ? zw1 : zw0;
            float* zw_prev    = (k & 1) ? zw0 : zw1;
            float* zwhat_cur  = (k & 1) ? zwhat1 : zwhat0;
            float* zwhat_prev = (k & 1) ? zwhat0 : zwhat1;

            // rel LSTM gates (ih+hh fused, K=736)
            mfma_gemm<0,0><<<dim3(16, 16), 256, 0, stream>>>(rin_k, RIN_LD, RIN_LD, W_rel, RIN_LD, 1024, bih_rel, bhh_rel, gates, 1024);
            lstm_rel<<<(NN*HIDD+255)/256, 256, 0, stream>>>(gates, h_r, c_r, rin_nx, tin);
            zw_kernel<<<(NN*3+255)/256, 256, 0, stream>>>(z_where_last, h_r, Wm_wh, bm_wh, zw_cur, out_zwhere, tin, rin_nx, k);
            glimpse_kernel<<<NN, 256, 0, stream>>>(img, zw_cur, tin, TIN_LD);
            fill_tin<<<(NN*359+255)/256, 256, 0, stream>>>(tin, zw_prev, zwhat_prev, z_what_last, hidden_last, k);
            // tem LSTM gates (ih+hh fused, K=3136)
            mfma_gemm<0,0><<<dim3(16, 16), 256, 0, stream>>>(tin, TIN_LD, TIN_LD, W_tem, TIN_LD, 1024, bih_tem, bhh_tem, gates, 1024);
            lstm_tem<<<(NN*HIDD+255)/256, 256, 0, stream>>>(gates, c_r, h_t, out_htemp, k);
            zwhat_kernel<<<(NN*50+255)/256, 256, 0, stream>>>(z_what_last, h_r, h_t, Wm_wt, bm_wt, zwhat_cur, out_zwhat, rin_nx, k);
            pres_kernel<<<NN/4, 256, 0, stream>>>(zwhat_cur, zw_cur, h_r, h_t, Wm_pr, bm_pr, Ws_pr, bs_pr, z_pres_last, out_zpres, k);
        }
    }
}

// Round 3
// 1516.302 us; speedup vs baseline: 5.5579x; 1.0862x over previous
//
#include <hip/hip_runtime.h>
#include <hip/hip_bf16.h>
#include <math.h>

typedef __attribute__((ext_vector_type(8))) short bf16x8;
typedef __attribute__((ext_vector_type(4))) float f32x4;
using bf16 = __hip_bfloat16;

constexpr int NN   = 2048;
constexpr int KO   = 8;
constexpr int IH   = 128, IW = 128;
constexpr int GS   = 50;
constexpr int GG2  = GS*GS;      // 2500
constexpr int HIDD = 256;
// rin layout: [enc 0..100 | zwl 100..103 | pzw 103..106 | zwhatl 106..156 | pzwhat 156..206 | hl 206..462 | h_r 462..718 | pad..736]
constexpr int RIN_LD = 736;
// tin layout: [g2 0..2500 | zw 2500..2503 | pzw 2503..2506 | zwhatl 2506..2556 | pzwhat 2556..2606 | hl 2606..2862 | h_r2 2862..3118 | pad..3136]
constexpr int TIN_LD = 3136;
constexpr int G1_LD  = 2528;     // 2500 + zero-padded weight cols

__device__ __forceinline__ float sigm(float x) { return 1.f/(1.f+expf(-x)); }

// ================= MFMA GEMM v2: fragment-major LDS + register prefetch ==================
// C[N][M] = A[N][Kd] @ W[M][Kd]^T. Tile BN=128 x BM=64, BK=32. 4 waves, wave tile 64x32.
// LDS layout: As16[g*64 + lane] (16B units) = A[g*16 + (lane&15)][k0 + (lane>>4)*8 ..+8)
// -> every wave frag read and every wave staging write is a contiguous 1024B row-group.
template<int OUT_BF16, int RELU>
__global__ __launch_bounds__(256) void mfma_gemm(
    const bf16* __restrict__ A, int lda, int Kd,
    const bf16* __restrict__ Wt, int ldw, int M,
    const float* __restrict__ b1, const float* __restrict__ b2,
    void* __restrict__ Cout, int ldc)
{
    __shared__ bf16x8 As16[512];   // 8 row-groups x 64 lanes
    __shared__ bf16x8 Bs16[256];   // 4 col-groups x 64 lanes
    const int tid  = threadIdx.x;
    const int n0   = blockIdx.y*128;
    const int m0   = blockIdx.x*64;
    const int wave = tid>>6, lane = tid&63;
    const int q    = lane>>4, r = lane&15;
    const int wy   = wave>>1, wx = wave&1;

    const int row  = tid>>2, part = tid&3;
    const bf16* A0 = A + (size_t)(n0+row)*lda    + part*8;
    const bf16* A1 = A + (size_t)(n0+row+64)*lda + part*8;
    const int   wm = m0 + row;
    const bool  wok = wm < M;
    const bf16* Wp = Wt + (size_t)(wok ? wm : 0)*ldw + part*8;
    const int dstA = (row>>4)*64 + part*16 + (row&15);

    f32x4 acc[4][2] = {};
    const bf16x8 z8 = {};
    bf16x8 pa0 = *(const bf16x8*)A0;
    bf16x8 pa1 = *(const bf16x8*)A1;
    bf16x8 pw  = *(const bf16x8*)Wp;

    for (int k0 = 0; k0 < Kd; k0 += 32) {
        __syncthreads();
        As16[dstA]       = pa0;
        As16[dstA + 256] = pa1;
        Bs16[dstA]       = wok ? pw : z8;
        __syncthreads();
        if (k0 + 32 < Kd) {               // prefetch next tile while MFMA phase runs
            pa0 = *(const bf16x8*)(A0 + k0 + 32);
            pa1 = *(const bf16x8*)(A1 + k0 + 32);
            pw  = *(const bf16x8*)(Wp + k0 + 32);
        }
        bf16x8 av[4], bv[2];
        #pragma unroll
        for (int i=0;i<4;i++)  av[i] = As16[(wy*4+i)*64 + lane];
        #pragma unroll
        for (int j=0;j<2;j++)  bv[j] = Bs16[(wx*2+j)*64 + lane];
        #pragma unroll
        for (int i=0;i<4;i++)
            #pragma unroll
            for (int j=0;j<2;j++)
                acc[i][j] = __builtin_amdgcn_mfma_f32_16x16x32_bf16(av[i], bv[j], acc[i][j], 0, 0, 0);
    }

    const int crow = n0 + wy*64 + q*4;
    const int ccol = m0 + wx*32 + r;
    #pragma unroll
    for (int j=0;j<2;j++) {
        int col = ccol + j*16;
        if (col < M) {
            float bias = 0.f;
            if (b1) bias += b1[col];
            if (b2) bias += b2[col];
            #pragma unroll
            for (int i=0;i<4;i++) {
                #pragma unroll
                for (int reg=0;reg<4;reg++) {
                    float v = acc[i][j][reg] + bias;
                    if (RELU) v = fmaxf(v, 0.f);
                    size_t idx = (size_t)(crow + i*16 + reg)*ldc + col;
                    if (OUT_BF16) ((bf16*)Cout)[idx] = __float2bfloat16(v);
                    else          ((float*)Cout)[idx] = v;
                }
            }
        }
    }
}

// ================= glimpse core: 2500 bilinear points, pair-processed =================
__device__ __forceinline__ void glimpse_points(const float* __restrict__ im,
                                               float s, float tx, float ty,
                                               bf16* __restrict__ drow) {
    const float GXS = 2.0f/49.0f;
    const float txp = tx + 1.0f, typ = ty + 1.0f;
    for (int p2 = threadIdx.x; p2 < 1250; p2 += 256) {
        int i = p2 / 25;
        int j = (p2 - i*25) * 2;
        // shared y side
        float gy  = fmaf((float)i, GXS, -1.0f);
        float py  = fmaf(s, gy, typ) * 63.5f;
        float y0f = floorf(py); float fy = py - y0f; int y0 = (int)y0f;
        float wy0 = ((unsigned)y0     < 128u) ? (1.f - fy) : 0.f;
        float wy1 = ((unsigned)(y0+1) < 128u) ? fy         : 0.f;
        const float* r0 = im + min(max(y0,  0),127)*IW;
        const float* r1 = im + min(max(y0+1,0),127)*IW;
        // x side a
        float gxa = fmaf((float)j, GXS, -1.0f);
        float pxa = fmaf(s, gxa, txp) * 63.5f;
        float xa0f = floorf(pxa); float fa = pxa - xa0f; int xa0 = (int)xa0f;
        float wa0 = ((unsigned)xa0     < 128u) ? (1.f - fa) : 0.f;
        float wa1 = ((unsigned)(xa0+1) < 128u) ? fa         : 0.f;
        int xa0c = min(max(xa0,  0),127), xa1c = min(max(xa0+1,0),127);
        // x side b
        float gxb = fmaf((float)(j+1), GXS, -1.0f);
        float pxb = fmaf(s, gxb, txp) * 63.5f;
        float xb0f = floorf(pxb); float fb = pxb - xb0f; int xb0 = (int)xb0f;
        float wb0 = ((unsigned)xb0     < 128u) ? (1.f - fb) : 0.f;
        float wb1 = ((unsigned)(xb0+1) < 128u) ? fb         : 0.f;
        int xb0c = min(max(xb0,  0),127), xb1c = min(max(xb0+1,0),127);

        float va = fmaf(wy1, fmaf(wa0, r1[xa0c], wa1*r1[xa1c]),
                   wy0 *     fmaf(wa0, r0[xa0c], wa1*r0[xa1c]));
        float vb = fmaf(wy1, fmaf(wb0, r1[xb0c], wb1*r1[xb1c]),
                   wy0 *     fmaf(wb0, r0[xb0c], wb1*r0[xb1c]));

        bf16 b0 = __float2bfloat16(va), b1 = __float2bfloat16(vb);
        unsigned short u0, u1;
        __builtin_memcpy(&u0, &b0, 2); __builtin_memcpy(&u1, &b1, 2);
        *(unsigned int*)(drow + i*GS + j) = (unsigned)u0 | ((unsigned)u1 << 16);
    }
}

// batched glimpse1 (CH steps at once)
__global__ __launch_bounds__(256) void glimpse_batch(const float* __restrict__ img,
                                                     const float* __restrict__ z,
                                                     bf16* __restrict__ dst, int ldd) {
    int b = blockIdx.x;
    const float* im = img + (size_t)(b & (NN-1))*IH*IW;
    glimpse_points(im, z[b*3+0], z[b*3+1], z[b*3+2], dst + (size_t)b*ldd);
}

// per-step glimpse2 fused with tin concat fill (cols 2500..2862)
__global__ __launch_bounds__(256) void glimpse2_fused(const float* __restrict__ img,
                                                      const float* __restrict__ zw_cur,
                                                      const float* __restrict__ zw_prev,
                                                      const float* __restrict__ zwhat_prev,
                                                      const float* __restrict__ z_what_last,
                                                      const float* __restrict__ hidden_last,
                                                      bf16* __restrict__ tin, int k) {
    int n = blockIdx.x;
    const float* im = img + (size_t)n*IH*IW;
    float s  = zw_cur[n*3+0];
    float tx = zw_cur[n*3+1];
    float ty = zw_cur[n*3+2];
    bf16* trow = tin + (size_t)n*TIN_LD;
    glimpse_points(im, s, tx, ty, trow);
    for (int c = threadIdx.x; c < 362; c += 256) {
        float v;
        if      (c <   3) v = (c==0) ? s : ((c==1) ? tx : ty);
        else if (c <   6) v = zw_prev[n*3 + c-3];
        else if (c <  56) v = z_what_last[((size_t)n*KO + k)*50 + c-6];
        else if (c < 106) v = zwhat_prev[n*50 + c-56];
        else              v = hidden_last[((size_t)n*KO + k)*HIDD + c-106];
        trow[2500 + c] = __float2bfloat16(v);
    }
}

// ================= small / preamble kernels =================
__global__ void zero_f32(float* __restrict__ p, int n) {
    int i = blockIdx.x*blockDim.x + threadIdx.x;
    if (i < n) p[i] = 0.f;
}

__global__ void repack_w(const float* __restrict__ s1, int K1,
                         const float* __restrict__ s2, int K2,
                         bf16* __restrict__ dst, int ldd, int M) {
    int gid = blockIdx.x*blockDim.x + threadIdx.x;
    if (gid >= M*ldd) return;
    int m = gid / ldd, c = gid - m*ldd;
    float v = 0.f;
    if (c < K1)           v = s1[(size_t)m*K1 + c];
    else if (c < K1+K2)   v = s2[(size_t)m*K2 + (c-K1)];
    dst[gid] = __float2bfloat16(v);
}

__global__ void zwb_all_kernel(const float* __restrict__ hidden_last,
                               const float* __restrict__ z_where_last,
                               const float* __restrict__ Wl, const float* __restrict__ bl,
                               float* __restrict__ zwb_all) {
    int gid = blockIdx.x*blockDim.x + threadIdx.x;
    if (gid >= KO*NN*3) return;
    int j = gid % 3; int rn = gid/3; int n = rn & (NN-1); int s = rn >> 11;
    const float* hl = hidden_last + ((size_t)n*KO + s)*HIDD;
    const float* w  = Wl + j*HIDD;
    float acc = bl[j];
    for (int i=0;i<HIDD;i++) acc = fmaf(hl[i], w[i], acc);
    zwb_all[gid] = fmaxf(acc, 0.f) + z_where_last[((size_t)n*KO + s)*3 + j];
}

__global__ void fill_rin_static(bf16* __restrict__ rin,
                                const float* __restrict__ z_where_last,
                                const float* __restrict__ z_what_last,
                                const float* __restrict__ hidden_last,
                                int base, int CH) {
    int gid = blockIdx.x*blockDim.x + threadIdx.x;
    if (gid >= CH*NN*309) return;
    int c = gid % 309; int rn = gid/309; int n = rn & (NN-1); int sl = rn >> 11;
    int k = base + sl;
    float v; int col;
    if (c < 3)       { col = 100 + c;      v = z_where_last[((size_t)n*KO + k)*3 + c]; }
    else if (c < 53) { col = 106 + (c-3);  v = z_what_last[((size_t)n*KO + k)*50 + (c-3)]; }
    else             { col = 206 + (c-53); v = hidden_last[((size_t)n*KO + k)*HIDD + (c-53)]; }
    rin[(size_t)rn*RIN_LD + col] = __float2bfloat16(v);
}

__global__ void zero_rin_carry(bf16* __restrict__ rin0) {
    int gid = blockIdx.x*blockDim.x + threadIdx.x;
    if (gid >= NN*309) return;
    int c = gid % 309, n = gid/309;
    int col = (c < 3) ? 103+c : ((c < 53) ? 156+(c-3) : 462+(c-53));
    rin0[(size_t)n*RIN_LD + col] = __float2bfloat16(0.f);
}

// ================= fused step kernels (block per n) =================
// rel LSTM elementwise + zw linear. Writes h_r, c_r, zw_cur, out_zwhere, carry cols.
__global__ __launch_bounds__(256) void rel_fused(
    const float* __restrict__ gates, float* __restrict__ h_r, float* __restrict__ c_r,
    const float* __restrict__ z_where_last,
    const float* __restrict__ Wm_wh, const float* __restrict__ bm_wh,
    float* __restrict__ zw_cur, float* __restrict__ out_zwhere,
    bf16* __restrict__ rin_next, bf16* __restrict__ tin, int k)
{
    __shared__ float hs[256];
    int n = blockIdx.x, j = threadIdx.x;
    const float* g = gates + (size_t)n*1024;
    float ig = sigm(g[j]);
    float fg = sigm(g[256+j]);
    float gg = tanhf(g[512+j]);
    float og = sigm(g[768+j]);
    int cidx = n*256 + j;
    float c2 = fg*c_r[cidx] + ig*gg;
    float hv = og*tanhf(c2);
    c_r[cidx] = c2;
    h_r[cidx] = hv;
    hs[j] = hv;
    bf16 hb = __float2bfloat16(hv);
    rin_next[(size_t)n*RIN_LD + 462 + j] = hb;
    tin[(size_t)n*TIN_LD + 2862 + j]     = hb;
    __syncthreads();
    int w = j >> 6, lane = j & 63;
    if (w < 3) {
        const float* wt = Wm_wh + w*259;
        float s = 0.f;
        for (int i = lane; i < 256; i += 64) s = fmaf(hs[i], wt[3+i], s);
        #pragma unroll
        for (int off = 32; off; off >>= 1) s += __shfl_down(s, off);
        if (lane == 0) {
            const float* zwl = z_where_last + ((size_t)n*KO + k)*3;
            float acc = bm_wh[w] + s;
            for (int i = 0; i < 3; i++) acc = fmaf(zwl[i], wt[i], acc);
            zw_cur[n*3+w] = acc;
            out_zwhere[((size_t)n*KO + k)*3 + w] = acc;
            rin_next[(size_t)n*RIN_LD + 103 + w] = __float2bfloat16(acc);
        }
    }
}

// tem LSTM elementwise + zwhat linear + pres. LDS: [zwhatl 0..50 | zw 50..53 | hr 53..309 | ht 309..565 | zwhat 565..615]
__global__ __launch_bounds__(256) void tem_fused(
    const float* __restrict__ gates, const float* __restrict__ c_r, const float* __restrict__ h_r,
    const float* __restrict__ z_what_last,
    const float* __restrict__ Wm_wt, const float* __restrict__ bm_wt,
    const float* __restrict__ Wm_pr, const float* __restrict__ bm_pr,
    const float* __restrict__ Ws_pr, const float* __restrict__ bs_pr,
    const float* __restrict__ zw_cur, const float* __restrict__ z_pres_last,
    float* __restrict__ zwhat_cur, float* __restrict__ out_zwhat,
    float* __restrict__ out_htemp, float* __restrict__ out_zpres,
    bf16* __restrict__ rin_next, int k)
{
    __shared__ float L[615];
    int n = blockIdx.x, j = threadIdx.x;
    const float* g = gates + (size_t)n*1024;
    float ig = sigm(g[j]);
    float fg = sigm(g[256+j]);
    float gg = tanhf(g[512+j]);
    float og = sigm(g[768+j]);
    float c2 = fg*c_r[n*256+j] + ig*gg;
    float hv = og*tanhf(c2);
    out_htemp[((size_t)n*KO + k)*HIDD + j] = hv;
    L[309+j] = hv;
    L[53+j]  = h_r[n*256+j];
    if (j < 50)      L[j]  = z_what_last[((size_t)n*KO + k)*50 + j];
    else if (j < 53) L[j]  = zw_cur[n*3 + (j-50)];
    __syncthreads();
    // zwhat: 50 outputs x 562-dot over [zwhatl, hr, ht], quad-split
    if (j < 200) {
        int m = j >> 2, part = j & 3;
        const float* wt = Wm_wt + m*562;
        float s = 0.f;
        for (int i = part; i < 562; i += 4) {
            float v = (i < 50) ? L[i] : L[i+3];
            s = fmaf(v, wt[i], s);
        }
        s += __shfl_down(s, 2);
        s += __shfl_down(s, 1);
        if (part == 0) {
            float acc = s + bm_wt[m];
            zwhat_cur[n*50+m] = acc;
            out_zwhat[((size_t)n*KO + k)*50 + m] = acc;
            rin_next[(size_t)n*RIN_LD + 156 + m] = __float2bfloat16(acc);
            L[565+m] = acc;
        }
    }
    __syncthreads();
    // pres: zp_cal = [zwhat(50), zw(3), hr(256), ht(256)]
    if (j < 64) {
        float s1 = 0.f, s2 = 0.f;
        for (int i = j; i < 565; i += 64) {
            float v = (i < 50) ? L[565+i] : L[i];
            s1 = fmaf(v, Wm_pr[i], s1);
            s2 = fmaf(v, Ws_pr[i], s2);
        }
        #pragma unroll
        for (int off = 32; off; off >>= 1) { s1 += __shfl_down(s1,off); s2 += __shfl_down(s2,off); }
        if (j == 0) {
            float p = sigm(s1 + bm_pr[0]) * sigm(s2 + bs_pr[0]);
            out_zpres[(size_t)n*KO + k] = p * z_pres_last[(size_t)n*KO + k];
        }
    }
}

extern "C" void kernel_launch(void* const* d_in, const int* in_sizes, int n_in,
                              void* d_out, int out_size, void* d_ws, size_t ws_size,
                              hipStream_t stream) {
    (void)in_sizes; (void)n_in; (void)out_size;
    const float* img          = (const float*)d_in[0];
    const float* z_what_last  = (const float*)d_in[1];
    const float* z_where_last = (const float*)d_in[2];
    const float* z_pres_last  = (const float*)d_in[3];
    const float* hidden_last  = (const float*)d_in[4];
    const float* W_loca = (const float*)d_in[5];
    const float* b_loca = (const float*)d_in[6];
    const float* Wg     = (const float*)d_in[7];
    const float* bg     = (const float*)d_in[8];
    const float* Wih_rel = (const float*)d_in[9];
    const float* Whh_rel = (const float*)d_in[10];
    const float* bih_rel = (const float*)d_in[11];
    const float* bhh_rel = (const float*)d_in[12];
    const float* Wih_tem = (const float*)d_in[13];
    const float* Whh_tem = (const float*)d_in[14];
    const float* bih_tem = (const float*)d_in[15];
    const float* bhh_tem = (const float*)d_in[16];
    const float* Wm_wh = (const float*)d_in[17];
    const float* bm_wh = (const float*)d_in[18];
    const float* Wm_wt = (const float*)d_in[21];
    const float* bm_wt = (const float*)d_in[22];
    const float* Wm_pr = (const float*)d_in[25];
    const float* bm_pr = (const float*)d_in[26];
    const float* Ws_pr = (const float*)d_in[27];
    const float* bs_pr = (const float*)d_in[28];

    char* base_p = (char*)d_ws;
    size_t off = 0;
    auto carve = [&](size_t bytes) -> char* {
        char* r = base_p + off;
        off += (bytes + 255) & ~(size_t)255;
        return r;
    };
    bf16*  tin      = (bf16*) carve((size_t)NN*TIN_LD*2);
    float* gates    = (float*)carve((size_t)NN*1024*4);
    bf16*  W_tem    = (bf16*) carve((size_t)1024*TIN_LD*2);
    bf16*  W_rel    = (bf16*) carve((size_t)1024*RIN_LD*2);
    bf16*  Wg_bf    = (bf16*) carve((size_t)100*G1_LD*2);
    float* zwb_all  = (float*)carve((size_t)KO*NN*3*4);
    float* h_r      = (float*)carve((size_t)NN*HIDD*4);
    // zero block: c_r, zw1, zwhat1 contiguous
    float* c_r      = (float*)carve((size_t)NN*HIDD*4);
    float* zw1      = (float*)carve((size_t)NN*3*4);
    float* zwhat1   = (float*)carve((size_t)NN*50*4);
    float* zw0      = (float*)carve((size_t)NN*3*4);
    float* zwhat0   = (float*)carve((size_t)NN*50*4);
    size_t fixed_bytes = off;

    int CH = 1;
    for (int cand : {8, 4, 2}) {
        size_t need = fixed_bytes
                    + (((size_t)cand*NN*G1_LD*2 + 255) & ~(size_t)255)
                    + (((size_t)cand*NN*RIN_LD*2 + 255) & ~(size_t)255);
        if (need <= ws_size) { CH = cand; break; }
    }
    bf16* g1 = nullptr; int g1ld;
    bf16* rin;
    if (CH > 1) {
        g1   = (bf16*)carve((size_t)CH*NN*G1_LD*2);
        rin  = (bf16*)carve((size_t)CH*NN*RIN_LD*2);
        g1ld = G1_LD;
    } else {
        rin  = (bf16*)carve((size_t)NN*RIN_LD*2);
        g1   = tin;          // glimpse1 -> tin cols 0..2500; Wg pad cols are zero
        g1ld = TIN_LD;
    }

    float* out        = (float*)d_out;
    float* out_zwhat  = out;
    float* out_zwhere = out + (size_t)NN*KO*50;
    float* out_zpres  = out_zwhere + (size_t)NN*KO*3;
    float* out_htemp  = out_zpres + (size_t)NN*KO;

    // ---- preamble (carry-independent) ----
    {
        int nz = NN*(HIDD + 3 + 50);   // c_r, zw1, zwhat1
        zero_f32<<<(nz+255)/256, 256, 0, stream>>>(c_r, nz);
    }
    zero_rin_carry<<<(NN*309+255)/256, 256, 0, stream>>>(rin);
    repack_w<<<((1024*RIN_LD)+255)/256, 256, 0, stream>>>(Wih_rel, 462, Whh_rel, 256, W_rel, RIN_LD, 1024);
    repack_w<<<((1024*TIN_LD)+255)/256, 256, 0, stream>>>(Wih_tem, 2862, Whh_tem, 256, W_tem, TIN_LD, 1024);
    repack_w<<<((100*G1_LD)+255)/256, 256, 0, stream>>>(Wg, 2500, nullptr, 0, Wg_bf, G1_LD, 100);
    zwb_all_kernel<<<(KO*NN*3+255)/256, 256, 0, stream>>>(hidden_last, z_where_last, W_loca, b_loca, zwb_all);

    for (int cbase = 0; cbase < KO; cbase += CH) {
        fill_rin_static<<<(CH*NN*309+255)/256, 256, 0, stream>>>(rin, z_where_last, z_what_last, hidden_last, cbase, CH);
        glimpse_batch<<<CH*NN, 256, 0, stream>>>(img, zwb_all + (size_t)cbase*NN*3, g1, g1ld);
        mfma_gemm<1,1><<<dim3(2, CH*16), 256, 0, stream>>>(g1, g1ld, G1_LD, Wg_bf, G1_LD, 100, bg, nullptr, rin, RIN_LD);

        for (int s = 0; s < CH; ++s) {
            int k = cbase + s;
            bf16* rin_k  = rin + (size_t)s*NN*RIN_LD;
            bf16* rin_nx = rin + (size_t)((s+1)%CH)*NN*RIN_LD;
            float* zw_cur     = (k & 1) ? zw1 : zw0;
            float* zw_prev    = (k & 1) ? zw0 : zw1;
            float* zwhat_cur  = (k & 1) ? zwhat1 : zwhat0;
            float* zwhat_prev = (k & 1) ? zwhat0 : zwhat1;

            mfma_gemm<0,0><<<dim3(16, 16), 256, 0, stream>>>(rin_k, RIN_LD, RIN_LD, W_rel, RIN_LD, 1024, bih_rel, bhh_rel, gates, 1024);
            rel_fused<<<NN, 256, 0, stream>>>(gates, h_r, c_r, z_where_last, Wm_wh, bm_wh, zw_cur, out_zwhere, rin_nx, tin, k);
            glimpse2_fused<<<NN, 256, 0, stream>>>(img, zw_cur, zw_prev, zwhat_prev, z_what_last, hidden_last, tin, k);
            mfma_gemm<0,0><<<dim3(16, 16), 256, 0, stream>>>(tin, TIN_LD, TIN_LD, W_tem, TIN_LD, 1024, bih_tem, bhh_tem, gates, 1024);
            tem_fused<<<NN, 256, 0, stream>>>(gates, c_r, h_r, z_what_last, Wm_wt, bm_wt, Wm_pr, bm_pr, Ws_pr, bs_pr,
                                              zw_cur, z_pres_last, zwhat_cur, out_zwhat, out_htemp, out_zpres, rin_nx, k);
        }
    }
}

// Round 4
// 1348.370 us; speedup vs baseline: 6.2502x; 1.1245x over previous
//
#include <hip/hip_runtime.h>
#include <hip/hip_bf16.h>
#include <math.h>

typedef __attribute__((ext_vector_type(8))) short bf16x8;
typedef __attribute__((ext_vector_type(4))) float f32x4;
using bf16 = __hip_bfloat16;

constexpr int NN   = 2048;
constexpr int KO   = 8;
constexpr int IH   = 128, IW = 128;
constexpr int GS   = 50;
constexpr int GG2  = GS*GS;      // 2500
constexpr int HIDD = 256;
// rin layout: [enc 0..100 | zwl 100..103 | pzw 103..106 | zwhatl 106..156 | pzwhat 156..206 | hl 206..462 | h_r 462..718 | pad..768]
constexpr int RIN_LD = 768;      // multiple of 64
// tin layout: [g2 0..2500 | zw 2500..2503 | pzw 2503..2506 | zwhatl 2506..2556 | pzwhat 2556..2606 | hl 2606..2862 | h_r2 2862..3118 | pad..3136]
constexpr int TIN_LD = 3136;     // 49*64
constexpr int G1_LD  = 2560;     // 40*64 (2500 + zero-padded weight cols)

__device__ __forceinline__ float sigm(float x) { return 1.f/(1.f+expf(-x)); }

// ================= MFMA GEMM v3: 64x64 tile, BK=64, 2 blocks/CU ==================
// C[N][M] = A[N][Kd] @ W[M][Kd]^T. 4 waves, wave tile 32x32 (2x2 16x16x32 frags).
// Fragment-major LDS: group g (rowgroup*2+khalf) at As16[g*64 + lane]; every wave
// read and staging write is a contiguous 1024B row-group -> conflict-free.
// Kd must be a multiple of 64; N multiple of 64; W rows >= M handled by clamp+zero.
template<int OUT_BF16, int RELU>
__global__ __launch_bounds__(256, 2) void mfma_gemm(
    const bf16* __restrict__ A, int lda, int Kd,
    const bf16* __restrict__ Wt, int ldw, int M,
    const float* __restrict__ b1, const float* __restrict__ b2,
    void* __restrict__ Cout, int ldc)
{
    __shared__ bf16x8 As16[512];   // 4 rowgroups x 2 khalves x 64 lanes (8 KB)
    __shared__ bf16x8 Bs16[512];
    const int tid  = threadIdx.x;
    const int n0   = blockIdx.y*64;
    const int m0   = blockIdx.x*64;
    const int wave = tid>>6, lane = tid&63;
    const int wy   = wave>>1, wx = wave&1;

    const int row = tid>>2, part = tid&3;
    const bf16* Ap = A + (size_t)(n0+row)*lda + part*8;
    const int   wm = m0 + row;
    const bool  wok = wm < M;
    const bf16* Wp = Wt + (size_t)(wok ? wm : 0)*ldw + part*8;
    const int dst0 = ((row>>4)*2+0)*64 + part*16 + (row&15);
    const int dst1 = dst0 + 64;

    f32x4 acc[2][2] = {};
    const bf16x8 z8 = {};
    bf16x8 pa0 = *(const bf16x8*)Ap;
    bf16x8 pa1 = *(const bf16x8*)(Ap + 32);
    bf16x8 pw0 = *(const bf16x8*)Wp;
    bf16x8 pw1 = *(const bf16x8*)(Wp + 32);

    for (int k0 = 0; k0 < Kd; k0 += 64) {
        __syncthreads();
        As16[dst0] = pa0;
        As16[dst1] = pa1;
        Bs16[dst0] = wok ? pw0 : z8;
        Bs16[dst1] = wok ? pw1 : z8;
        __syncthreads();
        if (k0 + 64 < Kd) {            // prefetch next K-tile during MFMA phase
            pa0 = *(const bf16x8*)(Ap + k0 + 64);
            pa1 = *(const bf16x8*)(Ap + k0 + 96);
            pw0 = *(const bf16x8*)(Wp + k0 + 64);
            pw1 = *(const bf16x8*)(Wp + k0 + 96);
        }
        bf16x8 av[2][2], bv[2][2];
        #pragma unroll
        for (int i=0;i<2;i++)
            #pragma unroll
            for (int h=0;h<2;h++) av[i][h] = As16[((wy*2+i)*2+h)*64 + lane];
        #pragma unroll
        for (int j=0;j<2;j++)
            #pragma unroll
            for (int h=0;h<2;h++) bv[j][h] = Bs16[((wx*2+j)*2+h)*64 + lane];
        #pragma unroll
        for (int h=0;h<2;h++)
            #pragma unroll
            for (int i=0;i<2;i++)
                #pragma unroll
                for (int j=0;j<2;j++)
                    acc[i][j] = __builtin_amdgcn_mfma_f32_16x16x32_bf16(av[i][h], bv[j][h], acc[i][j], 0, 0, 0);
    }

    const int q = lane>>4, r = lane&15;
    #pragma unroll
    for (int j=0;j<2;j++) {
        int col = m0 + wx*32 + j*16 + r;
        if (col < M) {
            float bias = 0.f;
            if (b1) bias += b1[col];
            if (b2) bias += b2[col];
            #pragma unroll
            for (int i=0;i<2;i++) {
                #pragma unroll
                for (int reg=0;reg<4;reg++) {
                    float v = acc[i][j][reg] + bias;
                    if (RELU) v = fmaxf(v, 0.f);
                    size_t idx = (size_t)(n0 + wy*32 + i*16 + q*4 + reg)*ldc + col;
                    if (OUT_BF16) ((bf16*)Cout)[idx] = __float2bfloat16(v);
                    else          ((float*)Cout)[idx] = v;
                }
            }
        }
    }
}

// ================= glimpse core: 2500 bilinear points, pair-processed =================
__device__ __forceinline__ void glimpse_points(const float* __restrict__ im,
                                               float s, float tx, float ty,
                                               bf16* __restrict__ drow) {
    const float GXS = 2.0f/49.0f;
    const float txp = tx + 1.0f, typ = ty + 1.0f;
    for (int p2 = threadIdx.x; p2 < 1250; p2 += 256) {
        int i = p2 / 25;
        int j = (p2 - i*25) * 2;
        float gy  = fmaf((float)i, GXS, -1.0f);
        float py  = fmaf(s, gy, typ) * 63.5f;
        float y0f = floorf(py); float fy = py - y0f; int y0 = (int)y0f;
        float wy0 = ((unsigned)y0     < 128u) ? (1.f - fy) : 0.f;
        float wy1 = ((unsigned)(y0+1) < 128u) ? fy         : 0.f;
        const float* r0 = im + min(max(y0,  0),127)*IW;
        const float* r1 = im + min(max(y0+1,0),127)*IW;
        float gxa = fmaf((float)j, GXS, -1.0f);
        float pxa = fmaf(s, gxa, txp) * 63.5f;
        float xa0f = floorf(pxa); float fa = pxa - xa0f; int xa0 = (int)xa0f;
        float wa0 = ((unsigned)xa0     < 128u) ? (1.f - fa) : 0.f;
        float wa1 = ((unsigned)(xa0+1) < 128u) ? fa         : 0.f;
        int xa0c = min(max(xa0,  0),127), xa1c = min(max(xa0+1,0),127);
        float gxb = fmaf((float)(j+1), GXS, -1.0f);
        float pxb = fmaf(s, gxb, txp) * 63.5f;
        float xb0f = floorf(pxb); float fb = pxb - xb0f; int xb0 = (int)xb0f;
        float wb0 = ((unsigned)xb0     < 128u) ? (1.f - fb) : 0.f;
        float wb1 = ((unsigned)(xb0+1) < 128u) ? fb         : 0.f;
        int xb0c = min(max(xb0,  0),127), xb1c = min(max(xb0+1,0),127);

        float va = fmaf(wy1, fmaf(wa0, r1[xa0c], wa1*r1[xa1c]),
                   wy0 *     fmaf(wa0, r0[xa0c], wa1*r0[xa1c]));
        float vb = fmaf(wy1, fmaf(wb0, r1[xb0c], wb1*r1[xb1c]),
                   wy0 *     fmaf(wb0, r0[xb0c], wb1*r0[xb1c]));

        bf16 b0 = __float2bfloat16(va), b1 = __float2bfloat16(vb);
        unsigned short u0, u1;
        __builtin_memcpy(&u0, &b0, 2); __builtin_memcpy(&u1, &b1, 2);
        *(unsigned int*)(drow + i*GS + j) = (unsigned)u0 | ((unsigned)u1 << 16);
    }
}

__global__ __launch_bounds__(256) void glimpse_batch(const float* __restrict__ img,
                                                     const float* __restrict__ z,
                                                     bf16* __restrict__ dst, int ldd) {
    int b = blockIdx.x;
    const float* im = img + (size_t)(b & (NN-1))*IH*IW;
    glimpse_points(im, z[b*3+0], z[b*3+1], z[b*3+2], dst + (size_t)b*ldd);
}

__global__ __launch_bounds__(256) void glimpse2_fused(const float* __restrict__ img,
                                                      const float* __restrict__ zw_cur,
                                                      const float* __restrict__ zw_prev,
                                                      const float* __restrict__ zwhat_prev,
                                                      const float* __restrict__ z_what_last,
                                                      const float* __restrict__ hidden_last,
                                                      bf16* __restrict__ tin, int k) {
    int n = blockIdx.x;
    const float* im = img + (size_t)n*IH*IW;
    float s  = zw_cur[n*3+0];
    float tx = zw_cur[n*3+1];
    float ty = zw_cur[n*3+2];
    bf16* trow = tin + (size_t)n*TIN_LD;
    glimpse_points(im, s, tx, ty, trow);
    for (int c = threadIdx.x; c < 362; c += 256) {
        float v;
        if      (c <   3) v = (c==0) ? s : ((c==1) ? tx : ty);
        else if (c <   6) v = zw_prev[n*3 + c-3];
        else if (c <  56) v = z_what_last[((size_t)n*KO + k)*50 + c-6];
        else if (c < 106) v = zwhat_prev[n*50 + c-56];
        else              v = hidden_last[((size_t)n*KO + k)*HIDD + c-106];
        trow[2500 + c] = __float2bfloat16(v);
    }
}

// ================= small / preamble kernels =================
__global__ void zero_f32(float* __restrict__ p, int n) {
    int i = blockIdx.x*blockDim.x + threadIdx.x;
    if (i < n) p[i] = 0.f;
}

__global__ void repack_w(const float* __restrict__ s1, int K1,
                         const float* __restrict__ s2, int K2,
                         bf16* __restrict__ dst, int ldd, int M) {
    int gid = blockIdx.x*blockDim.x + threadIdx.x;
    if (gid >= M*ldd) return;
    int m = gid / ldd, c = gid - m*ldd;
    float v = 0.f;
    if (c < K1)           v = s1[(size_t)m*K1 + c];
    else if (c < K1+K2)   v = s2[(size_t)m*K2 + (c-K1)];
    dst[gid] = __float2bfloat16(v);
}

__global__ void zwb_all_kernel(const float* __restrict__ hidden_last,
                               const float* __restrict__ z_where_last,
                               const float* __restrict__ Wl, const float* __restrict__ bl,
                               float* __restrict__ zwb_all) {
    int gid = blockIdx.x*blockDim.x + threadIdx.x;
    if (gid >= KO*NN*3) return;
    int j = gid % 3; int rn = gid/3; int n = rn & (NN-1); int s = rn >> 11;
    const float* hl = hidden_last + ((size_t)n*KO + s)*HIDD;
    const float* w  = Wl + j*HIDD;
    float acc = bl[j];
    for (int i=0;i<HIDD;i++) acc = fmaf(hl[i], w[i], acc);
    zwb_all[gid] = fmaxf(acc, 0.f) + z_where_last[((size_t)n*KO + s)*3 + j];
}

__global__ void fill_rin_static(bf16* __restrict__ rin,
                                const float* __restrict__ z_where_last,
                                const float* __restrict__ z_what_last,
                                const float* __restrict__ hidden_last,
                                int base, int CH) {
    int gid = blockIdx.x*blockDim.x + threadIdx.x;
    if (gid >= CH*NN*309) return;
    int c = gid % 309; int rn = gid/309; int n = rn & (NN-1); int sl = rn >> 11;
    int k = base + sl;
    float v; int col;
    if (c < 3)       { col = 100 + c;      v = z_where_last[((size_t)n*KO + k)*3 + c]; }
    else if (c < 53) { col = 106 + (c-3);  v = z_what_last[((size_t)n*KO + k)*50 + (c-3)]; }
    else             { col = 206 + (c-53); v = hidden_last[((size_t)n*KO + k)*HIDD + (c-53)]; }
    rin[(size_t)rn*RIN_LD + col] = __float2bfloat16(v);
}

__global__ void zero_rin_carry(bf16* __restrict__ rin0) {
    int gid = blockIdx.x*blockDim.x + threadIdx.x;
    if (gid >= NN*309) return;
    int c = gid % 309, n = gid/309;
    int col = (c < 3) ? 103+c : ((c < 53) ? 156+(c-3) : 462+(c-53));
    rin0[(size_t)n*RIN_LD + col] = __float2bfloat16(0.f);
}

// ================= fused step kernels (block per n) =================
__global__ __launch_bounds__(256) void rel_fused(
    const float* __restrict__ gates, float* __restrict__ h_r, float* __restrict__ c_r,
    const float* __restrict__ z_where_last,
    const float* __restrict__ Wm_wh, const float* __restrict__ bm_wh,
    float* __restrict__ zw_cur, float* __restrict__ out_zwhere,
    bf16* __restrict__ rin_next, bf16* __restrict__ tin, int k)
{
    __shared__ float hs[256];
    int n = blockIdx.x, j = threadIdx.x;
    const float* g = gates + (size_t)n*1024;
    float ig = sigm(g[j]);
    float fg = sigm(g[256+j]);
    float gg = tanhf(g[512+j]);
    float og = sigm(g[768+j]);
    int cidx = n*256 + j;
    float c2 = fg*c_r[cidx] + ig*gg;
    float hv = og*tanhf(c2);
    c_r[cidx] = c2;
    h_r[cidx] = hv;
    hs[j] = hv;
    bf16 hb = __float2bfloat16(hv);
    rin_next[(size_t)n*RIN_LD + 462 + j] = hb;
    tin[(size_t)n*TIN_LD + 2862 + j]     = hb;
    __syncthreads();
    int w = j >> 6, lane = j & 63;
    if (w < 3) {
        const float* wt = Wm_wh + w*259;
        float s = 0.f;
        for (int i = lane; i < 256; i += 64) s = fmaf(hs[i], wt[3+i], s);
        #pragma unroll
        for (int off = 32; off; off >>= 1) s += __shfl_down(s, off);
        if (lane == 0) {
            const float* zwl = z_where_last + ((size_t)n*KO + k)*3;
            float acc = bm_wh[w] + s;
            for (int i = 0; i < 3; i++) acc = fmaf(zwl[i], wt[i], acc);
            zw_cur[n*3+w] = acc;
            out_zwhere[((size_t)n*KO + k)*3 + w] = acc;
            rin_next[(size_t)n*RIN_LD + 103 + w] = __float2bfloat16(acc);
        }
    }
}

// tem LSTM elementwise + zwhat linear + pres. LDS: [zwhatl 0..50 | zw 50..53 | hr 53..309 | ht 309..565 | zwhat 565..615]
__global__ __launch_bounds__(256) void tem_fused(
    const float* __restrict__ gates, const float* __restrict__ c_r, const float* __restrict__ h_r,
    const float* __restrict__ z_what_last,
    const float* __restrict__ Wm_wt, const float* __restrict__ bm_wt,
    const float* __restrict__ Wm_pr, const float* __restrict__ bm_pr,
    const float* __restrict__ Ws_pr, const float* __restrict__ bs_pr,
    const float* __restrict__ zw_cur, const float* __restrict__ z_pres_last,
    float* __restrict__ zwhat_cur, float* __restrict__ out_zwhat,
    float* __restrict__ out_htemp, float* __restrict__ out_zpres,
    bf16* __restrict__ rin_next, int k)
{
    __shared__ float L[615];
    int n = blockIdx.x, j = threadIdx.x;
    const float* g = gates + (size_t)n*1024;
    float ig = sigm(g[j]);
    float fg = sigm(g[256+j]);
    float gg = tanhf(g[512+j]);
    float og = sigm(g[768+j]);
    float c2 = fg*c_r[n*256+j] + ig*gg;
    float hv = og*tanhf(c2);
    out_htemp[((size_t)n*KO + k)*HIDD + j] = hv;
    L[309+j] = hv;
    L[53+j]  = h_r[n*256+j];
    if (j < 50)      L[j]  = z_what_last[((size_t)n*KO + k)*50 + j];
    else if (j < 53) L[j]  = zw_cur[n*3 + (j-50)];
    __syncthreads();
    if (j < 200) {
        int m = j >> 2, part = j & 3;
        const float* wt = Wm_wt + m*562;
        float s = 0.f;
        for (int i = part; i < 562; i += 4) {
            float v = (i < 50) ? L[i] : L[i+3];
            s = fmaf(v, wt[i], s);
        }
        s += __shfl_down(s, 2);
        s += __shfl_down(s, 1);
        if (part == 0) {
            float acc = s + bm_wt[m];
            zwhat_cur[n*50+m] = acc;
            out_zwhat[((size_t)n*KO + k)*50 + m] = acc;
            rin_next[(size_t)n*RIN_LD + 156 + m] = __float2bfloat16(acc);
            L[565+m] = acc;
        }
    }
    __syncthreads();
    if (j < 64) {
        float s1 = 0.f, s2 = 0.f;
        for (int i = j; i < 565; i += 64) {
            float v = (i < 50) ? L[565+i] : L[i];
            s1 = fmaf(v, Wm_pr[i], s1);
            s2 = fmaf(v, Ws_pr[i], s2);
        }
        #pragma unroll
        for (int off = 32; off; off >>= 1) { s1 += __shfl_down(s1,off); s2 += __shfl_down(s2,off); }
        if (j == 0) {
            float p = sigm(s1 + bm_pr[0]) * sigm(s2 + bs_pr[0]);
            out_zpres[(size_t)n*KO + k] = p * z_pres_last[(size_t)n*KO + k];
        }
    }
}

extern "C" void kernel_launch(void* const* d_in, const int* in_sizes, int n_in,
                              void* d_out, int out_size, void* d_ws, size_t ws_size,
                              hipStream_t stream) {
    (void)in_sizes; (void)n_in; (void)out_size;
    const float* img          = (const float*)d_in[0];
    const float* z_what_last  = (const float*)d_in[1];
    const float* z_where_last = (const float*)d_in[2];
    const float* z_pres_last  = (const float*)d_in[3];
    const float* hidden_last  = (const float*)d_in[4];
    const float* W_loca = (const float*)d_in[5];
    const float* b_loca = (const float*)d_in[6];
    const float* Wg     = (const float*)d_in[7];
    const float* bg     = (const float*)d_in[8];
    const float* Wih_rel = (const float*)d_in[9];
    const float* Whh_rel = (const float*)d_in[10];
    const float* bih_rel = (const float*)d_in[11];
    const float* bhh_rel = (const float*)d_in[12];
    const float* Wih_tem = (const float*)d_in[13];
    const float* Whh_tem = (const float*)d_in[14];
    const float* bih_tem = (const float*)d_in[15];
    const float* bhh_tem = (const float*)d_in[16];
    const float* Wm_wh = (const float*)d_in[17];
    const float* bm_wh = (const float*)d_in[18];
    const float* Wm_wt = (const float*)d_in[21];
    const float* bm_wt = (const float*)d_in[22];
    const float* Wm_pr = (const float*)d_in[25];
    const float* bm_pr = (const float*)d_in[26];
    const float* Ws_pr = (const float*)d_in[27];
    const float* bs_pr = (const float*)d_in[28];

    char* base_p = (char*)d_ws;
    size_t off = 0;
    auto carve = [&](size_t bytes) -> char* {
        char* r = base_p + off;
        off += (bytes + 255) & ~(size_t)255;
        return r;
    };
    bf16*  tin      = (bf16*) carve((size_t)NN*TIN_LD*2);
    float* gates    = (float*)carve((size_t)NN*1024*4);
    bf16*  W_tem    = (bf16*) carve((size_t)1024*TIN_LD*2);
    bf16*  W_rel    = (bf16*) carve((size_t)1024*RIN_LD*2);
    bf16*  Wg_bf    = (bf16*) carve((size_t)100*G1_LD*2);
    float* zwb_all  = (float*)carve((size_t)KO*NN*3*4);
    float* h_r      = (float*)carve((size_t)NN*HIDD*4);
    // zero block: c_r, zw1, zwhat1 contiguous
    float* c_r      = (float*)carve((size_t)NN*HIDD*4);
    float* zw1      = (float*)carve((size_t)NN*3*4);
    float* zwhat1   = (float*)carve((size_t)NN*50*4);
    float* zw0      = (float*)carve((size_t)NN*3*4);
    float* zwhat0   = (float*)carve((size_t)NN*50*4);
    size_t fixed_bytes = off;

    int CH = 1;
    for (int cand : {8, 4, 2}) {
        size_t need = fixed_bytes
                    + (((size_t)cand*NN*G1_LD*2 + 255) & ~(size_t)255)
                    + (((size_t)cand*NN*RIN_LD*2 + 255) & ~(size_t)255);
        if (need <= ws_size) { CH = cand; break; }
    }
    bf16* g1 = nullptr; int g1ld;
    bf16* rin;
    if (CH > 1) {
        g1   = (bf16*)carve((size_t)CH*NN*G1_LD*2);
        rin  = (bf16*)carve((size_t)CH*NN*RIN_LD*2);
        g1ld = G1_LD;
    } else {
        rin  = (bf16*)carve((size_t)NN*RIN_LD*2);
        g1   = tin;          // glimpse1 -> tin cols 0..2500; Wg pad cols (2500..2560) are zero
        g1ld = TIN_LD;
    }

    float* out        = (float*)d_out;
    float* out_zwhat  = out;
    float* out_zwhere = out + (size_t)NN*KO*50;
    float* out_zpres  = out_zwhere + (size_t)NN*KO*3;
    float* out_htemp  = out_zpres + (size_t)NN*KO;

    // ---- preamble (carry-independent) ----
    {
        int nz = NN*(HIDD + 3 + 50);   // c_r, zw1, zwhat1
        zero_f32<<<(nz+255)/256, 256, 0, stream>>>(c_r, nz);
    }
    zero_rin_carry<<<(NN*309+255)/256, 256, 0, stream>>>(rin);
    repack_w<<<((1024*RIN_LD)+255)/256, 256, 0, stream>>>(Wih_rel, 462, Whh_rel, 256, W_rel, RIN_LD, 1024);
    repack_w<<<((1024*TIN_LD)+255)/256, 256, 0, stream>>>(Wih_tem, 2862, Whh_tem, 256, W_tem, TIN_LD, 1024);
    repack_w<<<((100*G1_LD)+255)/256, 256, 0, stream>>>(Wg, 2500, nullptr, 0, Wg_bf, G1_LD, 100);
    zwb_all_kernel<<<(KO*NN*3+255)/256, 256, 0, stream>>>(hidden_last, z_where_last, W_loca, b_loca, zwb_all);

    for (int cbase = 0; cbase < KO; cbase += CH) {
        fill_rin_static<<<(CH*NN*309+255)/256, 256, 0, stream>>>(rin, z_where_last, z_what_last, hidden_last, cbase, CH);
        glimpse_batch<<<CH*NN, 256, 0, stream>>>(img, zwb_all + (size_t)cbase*NN*3, g1, g1ld);
        mfma_gemm<1,1><<<dim3(2, CH*32), 256, 0, stream>>>(g1, g1ld, G1_LD, Wg_bf, G1_LD, 100, bg, nullptr, rin, RIN_LD);

        for (int s = 0; s < CH; ++s) {
            int k = cbase + s;
            bf16* rin_k  = rin + (size_t)s*NN*RIN_LD;
            bf16* rin_nx = rin + (size_t)((s+1)%CH)*NN*RIN_LD;
            float* zw_cur     = (k & 1) ? zw1 : zw0;
            float* zw_prev    = (k & 1) ? zw0 : zw1;
            float* zwhat_cur  = (k & 1) ? zwhat1 : zwhat0;
            float* zwhat_prev = (k & 1) ? zwhat0 : zwhat1;

            mfma_gemm<0,0><<<dim3(16, 32), 256, 0, stream>>>(rin_k, RIN_LD, RIN_LD, W_rel, RIN_LD, 1024, bih_rel, bhh_rel, gates, 1024);
            rel_fused<<<NN, 256, 0, stream>>>(gates, h_r, c_r, z_where_last, Wm_wh, bm_wh, zw_cur, out_zwhere, rin_nx, tin, k);
            glimpse2_fused<<<NN, 256, 0, stream>>>(img, zw_cur, zw_prev, zwhat_prev, z_what_last, hidden_last, tin, k);
            mfma_gemm<0,0><<<dim3(16, 32), 256, 0, stream>>>(tin, TIN_LD, TIN_LD, W_tem, TIN_LD, 1024, bih_tem, bhh_tem, gates, 1024);
            tem_fused<<<NN, 256, 0, stream>>>(gates, c_r, h_r, z_what_last, Wm_wt, bm_wt, Wm_pr, bm_pr, Ws_pr, bs_pr,
                                              zw_cur, z_pres_last, zwhat_cur, out_zwhat, out_htemp, out_zpres, rin_nx, k);
        }
    }
}